// Round 1
// baseline (92.844 us; speedup 1.0000x reference)
//
#include <hip/hip_runtime.h>

#define THREADS 256

// ---------------------------------------------------------------------------
// Kernel 1: count segment starts per chunk (chunk = THREADS * E elements,
// each thread owns E contiguous elements).
// ---------------------------------------------------------------------------
__global__ void k_count_starts(const int* __restrict__ idx, int n, int E,
                               int* __restrict__ blockCounts) {
    int base = (blockIdx.x * THREADS + threadIdx.x) * E;
    int cnt = 0;
    for (int j = 0; j < E; ++j) {
        int p = base + j;
        if (p < n) {
            int v = idx[p];
            cnt += (p == 0) || (idx[p - 1] != v);
        }
    }
    __shared__ int sd[THREADS];
    sd[threadIdx.x] = cnt;
    __syncthreads();
    for (int off = THREADS >> 1; off > 0; off >>= 1) {
        if (threadIdx.x < off) sd[threadIdx.x] += sd[threadIdx.x + off];
        __syncthreads();
    }
    if (threadIdx.x == 0) blockCounts[blockIdx.x] = sd[0];
}

// ---------------------------------------------------------------------------
// Kernel 2: single-block exclusive scan of up to 1024 values.
// Optionally writes the total to *totalOut and writes tailArr[total] = tailVal
// (used to place the seg_off[n_seg] = n sentinel).
// ---------------------------------------------------------------------------
__global__ void k_scan1024(const int* __restrict__ in, int nb,
                           int* __restrict__ outExcl,
                           int* __restrict__ totalOut,
                           int* __restrict__ tailArr, int tailVal) {
    __shared__ int sc[1024];
    int tid = threadIdx.x;
    int v = (tid < nb) ? in[tid] : 0;
    sc[tid] = v;
    __syncthreads();
    for (int off = 1; off < 1024; off <<= 1) {
        int t = 0;
        if (tid >= off) t = sc[tid - off];
        __syncthreads();
        if (tid >= off) sc[tid] += t;
        __syncthreads();
    }
    if (tid < nb) outExcl[tid] = sc[tid] - v;   // exclusive
    if (tid == 1023) {
        int total = sc[1023];
        if (totalOut) *totalOut = total;
        if (tailArr) tailArr[total] = tailVal;
    }
}

// ---------------------------------------------------------------------------
// Kernel 3: emit start positions -> segOff[ordinal] = p.
// ---------------------------------------------------------------------------
__global__ void k_emit_starts(const int* __restrict__ idx, int n, int E,
                              const int* __restrict__ blockOffs,
                              int* __restrict__ segOff) {
    int tid = threadIdx.x;
    int base = (blockIdx.x * THREADS + tid) * E;
    int cnt = 0;
    for (int j = 0; j < E; ++j) {
        int p = base + j;
        if (p < n) cnt += (p == 0) || (idx[p - 1] != idx[p]);
    }
    __shared__ int sc[THREADS];
    sc[tid] = cnt;
    __syncthreads();
    for (int off = 1; off < THREADS; off <<= 1) {
        int t = 0;
        if (tid >= off) t = sc[tid - off];
        __syncthreads();
        if (tid >= off) sc[tid] += t;
        __syncthreads();
    }
    int myOff = blockOffs[blockIdx.x] + sc[tid] - cnt;   // exclusive within grid
    for (int j = 0; j < E; ++j) {
        int p = base + j;
        if (p < n && ((p == 0) || (idx[p - 1] != idx[p]))) segOff[myOff++] = p;
    }
}

// ---------------------------------------------------------------------------
// Kernel 4: per-chunk sums of tri counts C(c,2) over segments.
// segOff[nseg] == n sentinel must already be in place.
// ---------------------------------------------------------------------------
__global__ void k_tri_blocksums(const int* __restrict__ segOff,
                                const int* __restrict__ nsegPtr, int E,
                                int* __restrict__ triBlockSums) {
    int nseg = *nsegPtr;
    int base = (blockIdx.x * THREADS + threadIdx.x) * E;
    int sum = 0;
    for (int j = 0; j < E; ++j) {
        int s = base + j;
        if (s < nseg) {
            int c = segOff[s + 1] - segOff[s];
            sum += c * (c - 1) / 2;
        }
    }
    __shared__ int sd[THREADS];
    sd[threadIdx.x] = sum;
    __syncthreads();
    for (int off = THREADS >> 1; off > 0; off >>= 1) {
        if (threadIdx.x < off) sd[threadIdx.x] += sd[threadIdx.x + off];
        __syncthreads();
    }
    if (threadIdx.x == 0) triBlockSums[blockIdx.x] = sd[0];
}

// ---------------------------------------------------------------------------
// Kernel 5: emit tri_off[s] (exclusive prefix of C(c,2)).
// ---------------------------------------------------------------------------
__global__ void k_emit_trioff(const int* __restrict__ segOff,
                              const int* __restrict__ nsegPtr, int E,
                              const int* __restrict__ triBlockOffs,
                              int* __restrict__ triOff) {
    int nseg = *nsegPtr;
    int tid = threadIdx.x;
    int base = (blockIdx.x * THREADS + tid) * E;
    int cnt = 0;
    for (int j = 0; j < E; ++j) {
        int s = base + j;
        if (s < nseg) {
            int c = segOff[s + 1] - segOff[s];
            cnt += c * (c - 1) / 2;
        }
    }
    __shared__ int sc[THREADS];
    sc[tid] = cnt;
    __syncthreads();
    for (int off = 1; off < THREADS; off <<= 1) {
        int t = 0;
        if (tid >= off) t = sc[tid - off];
        __syncthreads();
        if (tid >= off) sc[tid] += t;
        __syncthreads();
    }
    int run = triBlockOffs[blockIdx.x] + sc[tid] - cnt;
    for (int j = 0; j < E; ++j) {
        int s = base + j;
        if (s < nseg) {
            int c = segOff[s + 1] - segOff[s];
            triOff[s] = run;
            run += c * (c - 1) / 2;
        }
    }
}

// ---------------------------------------------------------------------------
// Kernel 6 (hot): fill the T triples. Grid-stride over segments; each block
// enumerates one segment's M = C(c,2) ranks, decodes (a,b), writes coalesced.
// ---------------------------------------------------------------------------
__global__ void k_fill(const int* __restrict__ segOff,
                       const int* __restrict__ triOff,
                       const int* __restrict__ nsegPtr,
                       int* __restrict__ outI, int* __restrict__ outJ,
                       int* __restrict__ outK) {
    int nseg = *nsegPtr;
    for (int s = blockIdx.x; s < nseg; s += gridDim.x) {
        int baseP = segOff[s];
        int c = segOff[s + 1] - baseP;
        int M = c * (c - 1) / 2;
        int t0 = triOff[s];
        for (int r = threadIdx.x; r < M; r += THREADS) {
            int rr = M - 1 - r;
            // triangular-root decode: k = largest k with k(k+1)/2 <= rr
            int k = (int)floorf((sqrtf((float)(8 * rr + 1)) - 1.0f) * 0.5f);
            if (k < 0) k = 0;
            while ((k + 1) * (k + 2) / 2 <= rr) ++k;   // exact fix-up
            while (k * (k + 1) / 2 > rr) --k;
            int a = c - 2 - k;
            int b = c - 1 - (rr - k * (k + 1) / 2);
            int t = t0 + r;
            outI[t] = s;
            outJ[t] = baseP + a;
            outK[t] = baseP + b;
        }
    }
}

extern "C" void kernel_launch(void* const* d_in, const int* in_sizes, int n_in,
                              void* d_out, int out_size, void* d_ws, size_t ws_size,
                              hipStream_t stream) {
    const int* idx = (const int*)d_in[0];
    int n = in_sizes[0];
    int T = out_size / 3;
    int* out = (int*)d_out;
    int* ws = (int*)d_ws;

    // workspace layout (ints)
    int* nsegPtr      = ws;                    // [1]
    int* blockCounts  = ws + 16;               // [1024]
    int* blockOffs    = ws + 16 + 1024;        // [1024]
    int* triBlockSums = ws + 16 + 2048;        // [1024]
    int* triBlockOffs = ws + 16 + 3072;        // [1024]
    int* segOff       = ws + 16 + 4096;        // [n+1] (sentinel at nseg)
    int* triOff       = segOff + (n + 1);      // [n]

    // pick per-thread element count so #chunks <= 1024 (single-block scan)
    int E = 8;
    while ((long long)(n + THREADS * E - 1) / (THREADS * E) > 1024) E <<= 1;
    int chunk = THREADS * E;
    int NB = (n + chunk - 1) / chunk;

    hipLaunchKernelGGL(k_count_starts, dim3(NB), dim3(THREADS), 0, stream,
                       idx, n, E, blockCounts);
    hipLaunchKernelGGL(k_scan1024, dim3(1), dim3(1024), 0, stream,
                       blockCounts, NB, blockOffs, nsegPtr, segOff, n);
    hipLaunchKernelGGL(k_emit_starts, dim3(NB), dim3(THREADS), 0, stream,
                       idx, n, E, blockOffs, segOff);
    hipLaunchKernelGGL(k_tri_blocksums, dim3(NB), dim3(THREADS), 0, stream,
                       segOff, nsegPtr, E, triBlockSums);
    hipLaunchKernelGGL(k_scan1024, dim3(1), dim3(1024), 0, stream,
                       triBlockSums, NB, triBlockOffs, (int*)nullptr,
                       (int*)nullptr, 0);
    hipLaunchKernelGGL(k_emit_trioff, dim3(NB), dim3(THREADS), 0, stream,
                       segOff, nsegPtr, E, triBlockOffs, triOff);
    hipLaunchKernelGGL(k_fill, dim3(4096), dim3(THREADS), 0, stream,
                       segOff, triOff, nsegPtr, out, out + T, out + 2 * T);
}

// Round 2
// 86.038 us; speedup vs baseline: 1.0791x; 1.0791x over previous
//
#include <hip/hip_runtime.h>

#define THREADS 256

// ---------------------------------------------------------------------------
// Block helpers (each leaves sdata reusable: trailing __syncthreads()).
// ---------------------------------------------------------------------------
__device__ __forceinline__ int blockReduceSum(int v, int* sdata) {
    int tid = threadIdx.x;
    sdata[tid] = v;
    __syncthreads();
    for (int off = THREADS >> 1; off > 0; off >>= 1) {
        if (tid < off) sdata[tid] += sdata[tid + off];
        __syncthreads();
    }
    int r = sdata[0];
    __syncthreads();
    return r;
}

__device__ __forceinline__ int blockScanIncl(int v, int* sdata) {
    int tid = threadIdx.x;
    sdata[tid] = v;
    __syncthreads();
    for (int off = 1; off < THREADS; off <<= 1) {
        int t = 0;
        if (tid >= off) t = sdata[tid - off];
        __syncthreads();
        if (tid >= off) sdata[tid] += t;
        __syncthreads();
    }
    int r = sdata[tid];
    __syncthreads();
    return r;
}

// ---------------------------------------------------------------------------
// Kernel 1: per-chunk count of segment starts (chunk = THREADS*E elements).
// ---------------------------------------------------------------------------
__global__ void k_count(const int* __restrict__ idx, int n, int E,
                        int* __restrict__ chunkCnt) {
    __shared__ int sdata[THREADS];
    int base = (blockIdx.x * THREADS + threadIdx.x) * E;
    int cnt = 0;
    for (int j = 0; j < E; ++j) {
        int p = base + j;
        if (p < n) cnt += (p == 0) || (idx[p - 1] != idx[p]);
    }
    int tot = blockReduceSum(cnt, sdata);
    if (threadIdx.x == 0) chunkCnt[blockIdx.x] = tot;
}

// ---------------------------------------------------------------------------
// Kernel 2: emit start positions. Each block computes its own inter-chunk
// prefix redundantly (no serial scan kernel). Last chunk writes nseg +
// the segOff[nseg] = n sentinel.
// ---------------------------------------------------------------------------
__global__ void k_emit_starts(const int* __restrict__ idx, int n, int E, int NB,
                              const int* __restrict__ chunkCnt,
                              int* __restrict__ segOff,
                              int* __restrict__ nsegPtr) {
    __shared__ int sdata[THREADS];
    int tid = threadIdx.x;
    int c = blockIdx.x;

    int pv = 0;
    for (int i = tid; i < c; i += THREADS) pv += chunkCnt[i];
    int prefix = blockReduceSum(pv, sdata);

    int base = (c * THREADS + tid) * E;
    int cnt = 0;
    for (int j = 0; j < E; ++j) {
        int p = base + j;
        if (p < n) cnt += (p == 0) || (idx[p - 1] != idx[p]);
    }
    int incl = blockScanIncl(cnt, sdata);
    int off = prefix + incl - cnt;
    for (int j = 0; j < E; ++j) {
        int p = base + j;
        if (p < n && ((p == 0) || (idx[p - 1] != idx[p]))) segOff[off++] = p;
    }
    if (c == NB - 1 && tid == THREADS - 1) {
        int nseg = prefix + incl;
        *nsegPtr = nseg;
        segOff[nseg] = n;
    }
}

// ---------------------------------------------------------------------------
// Kernel 3: per-chunk sums of C(c,2) over segments. Blocks beyond the live
// segment range write 0 (harmless).
// ---------------------------------------------------------------------------
__global__ void k_tri_sums(const int* __restrict__ segOff,
                           const int* __restrict__ nsegPtr, int E,
                           int* __restrict__ triChunkSum) {
    __shared__ int sdata[THREADS];
    int nseg = *nsegPtr;
    int base = (blockIdx.x * THREADS + threadIdx.x) * E;
    int sum = 0;
    for (int j = 0; j < E; ++j) {
        int s = base + j;
        if (s < nseg) {
            int cc = segOff[s + 1] - segOff[s];
            sum += cc * (cc - 1) / 2;
        }
    }
    int tot = blockReduceSum(sum, sdata);
    if (threadIdx.x == 0) triChunkSum[blockIdx.x] = tot;
}

// ---------------------------------------------------------------------------
// Kernel 4: emit triOff[s] with redundant per-block prefix.
// ---------------------------------------------------------------------------
__global__ void k_emit_trioff(const int* __restrict__ segOff,
                              const int* __restrict__ nsegPtr, int E,
                              const int* __restrict__ triChunkSum,
                              int* __restrict__ triOff) {
    __shared__ int sdata[THREADS];
    int nseg = *nsegPtr;
    int tid = threadIdx.x;
    int c = blockIdx.x;

    int pv = 0;
    for (int i = tid; i < c; i += THREADS) pv += triChunkSum[i];
    int prefix = blockReduceSum(pv, sdata);

    int base = (c * THREADS + tid) * E;
    int cnt = 0;
    for (int j = 0; j < E; ++j) {
        int s = base + j;
        if (s < nseg) {
            int cc = segOff[s + 1] - segOff[s];
            cnt += cc * (cc - 1) / 2;
        }
    }
    int incl = blockScanIncl(cnt, sdata);
    int run = prefix + incl - cnt;
    for (int j = 0; j < E; ++j) {
        int s = base + j;
        if (s < nseg) {
            int cc = segOff[s + 1] - segOff[s];
            triOff[s] = run;
            run += cc * (cc - 1) / 2;
        }
    }
}

// ---------------------------------------------------------------------------
// Kernel 5 (hot): wave-per-segment fill. 64 lanes walk the segment's M ranks;
// stores are fully coalesced (256 B per wave-instruction per stream).
// ---------------------------------------------------------------------------
__global__ void k_fill(const int* __restrict__ segOff,
                       const int* __restrict__ triOff,
                       const int* __restrict__ nsegPtr,
                       int* __restrict__ outI, int* __restrict__ outJ,
                       int* __restrict__ outK) {
    int nseg = *nsegPtr;
    int wid = blockIdx.x * (THREADS / 64) + (threadIdx.x >> 6);
    int lane = threadIdx.x & 63;
    int nW = gridDim.x * (THREADS / 64);
    for (int s = wid; s < nseg; s += nW) {
        int baseP = segOff[s];
        int cc = segOff[s + 1] - baseP;
        int M = cc * (cc - 1) / 2;
        int t0 = triOff[s];
        for (int r = lane; r < M; r += 64) {
            int rr = M - 1 - r;
            int k = (int)floorf((sqrtf((float)(8 * rr + 1)) - 1.0f) * 0.5f);
            if (k < 0) k = 0;
            while ((k + 1) * (k + 2) / 2 <= rr) ++k;   // exact fix-up
            while (k * (k + 1) / 2 > rr) --k;
            int a = cc - 2 - k;
            int b = cc - 1 - (rr - k * (k + 1) / 2);
            int t = t0 + r;
            outI[t] = s;
            outJ[t] = baseP + a;
            outK[t] = baseP + b;
        }
    }
}

extern "C" void kernel_launch(void* const* d_in, const int* in_sizes, int n_in,
                              void* d_out, int out_size, void* d_ws, size_t ws_size,
                              hipStream_t stream) {
    const int* idx = (const int*)d_in[0];
    int n = in_sizes[0];
    int T = out_size / 3;
    int* out = (int*)d_out;
    int* ws = (int*)d_ws;

    // workspace layout (ints)
    int* nsegPtr     = ws;                    // [1]
    int* chunkCnt    = ws + 16;               // [1024]
    int* triChunkSum = ws + 16 + 1024;        // [1024]
    int* segOff      = ws + 16 + 2048;        // [n+1] (sentinel at nseg)
    int* triOff      = segOff + (n + 1);      // [n]

    // per-thread element count so #chunks <= 1024
    int E = 8;
    while ((long long)(n + THREADS * E - 1) / (THREADS * E) > 1024) E <<= 1;
    int chunk = THREADS * E;
    int NB = (n + chunk - 1) / chunk;

    hipLaunchKernelGGL(k_count, dim3(NB), dim3(THREADS), 0, stream,
                       idx, n, E, chunkCnt);
    hipLaunchKernelGGL(k_emit_starts, dim3(NB), dim3(THREADS), 0, stream,
                       idx, n, E, NB, chunkCnt, segOff, nsegPtr);
    hipLaunchKernelGGL(k_tri_sums, dim3(NB), dim3(THREADS), 0, stream,
                       segOff, nsegPtr, E, triChunkSum);
    hipLaunchKernelGGL(k_emit_trioff, dim3(NB), dim3(THREADS), 0, stream,
                       segOff, nsegPtr, E, triChunkSum, triOff);
    hipLaunchKernelGGL(k_fill, dim3(4096), dim3(THREADS), 0, stream,
                       segOff, triOff, nsegPtr, out, out + T, out + 2 * T);
}